// Round 1
// baseline (577.564 us; speedup 1.0000x reference)
//
#include <hip/hip_runtime.h>
#include <hip/hip_bf16.h>

typedef __hip_bfloat16 bf16;

// dtype-flexible scalar load: bf16 or f32 element i
__device__ __forceinline__ float ldf(const void* p, long i, bool isb) {
    return isb ? __bfloat162float(((const bf16*)p)[i]) : ((const float*)p)[i];
}

// Device-scope HW fp32 atomic (memory-side RMW on gfx950; ~32B EA traffic/op).
__device__ __forceinline__ void atomAddDev(float* p, float v) {
    unsafeAtomicAdd(p, v);
}

// Workgroup-scope fp32 atomic: no sc bits -> performed in the issuing XCD's
// local L2. ONLY correct when every atomic to a given address comes from one
// XCD — guaranteed here by indexing replicas with HW_REG_XCC_ID. Dirty lines
// are written back by the end-of-kernel release, so later kernels see sums.
__device__ __forceinline__ void atomAddL2(float* p, float v) {
    asm volatile("global_atomic_add_f32 %0, %1, off" :: "v"(p), "v"(v) : "memory");
}

__device__ __forceinline__ unsigned xccId() {
    unsigned x;
    asm("s_getreg_b32 %0, hwreg(HW_REG_XCC_ID)" : "=s"(x));
    return x;
}

// Per-tensor input dtype detection (selects f32/i32; kept for robustness).
// flags[0]: x bf16?  flags[1]: edge_attr bf16?  flags[2]: weights bf16?  flags[3]: idx int64?
__global__ void detect_kernel(const unsigned short* __restrict__ x16,
                              const unsigned short* __restrict__ ea16,
                              const unsigned short* __restrict__ we16,
                              const int* __restrict__ ei,
                              unsigned* __restrict__ flags)
{
    __shared__ int cnt[4];
    int t = threadIdx.x; // 256 threads
    if (t < 4) cnt[t] = 0;
    __syncthreads();
    auto sane = [](unsigned short u) { int ex = (u >> 7) & 0xFF; return ex >= 97 && ex <= 157; };
    if (sane(x16[t]))  atomicAdd(&cnt[0], 1);
    if (sane(ea16[t])) atomicAdd(&cnt[1], 1);
    if (t < 32 && sane(we16[t])) atomicAdd(&cnt[2], 1);
    if (t < 32 && ei[2 * t + 1] == 0) atomicAdd(&cnt[3], 1);
    __syncthreads();
    if (t == 0) {
        flags[0] = (cnt[0] >= 240) ? 1u : 0u;
        flags[1] = (cnt[1] >= 240) ? 1u : 0u;
        flags[2] = (cnt[2] >= 29) ? 1u : 0u;
        flags[3] = (cnt[3] == 32) ? 1u : 0u;
    }
}

// Pass A (single edge pass):
//   pair_pred -> d_out (f32), ex=exp(score) (+dst id if packed) -> tail ws,
//   rep[r][2d] += ex (denom), rep[r][2d+1] += ex*x[src], r = replica.
// l2mode: r = XCC_ID, atomics workgroup-scope (L2-local, 800KB/replica resident).
// else:   r = blockIdx&rmask, atomics device-scope (memory-side).
__global__ void passA_kernel(const void* __restrict__ x, const int* __restrict__ ei,
                             const void* __restrict__ ea,
                             const void* __restrict__ W_node, const void* __restrict__ W_edge,
                             float2* __restrict__ out_pp, float* __restrict__ tail,
                             float* __restrict__ rep,
                             const unsigned* __restrict__ flags,
                             int E, int twoN, int rmask, int l2mode, int packed)
{
    __shared__ float wn[4];
    __shared__ float we[32];
    const bool fx = flags[0] != 0, fe = flags[1] != 0;
    const bool fw = flags[2] != 0, i64 = flags[3] != 0;
    {
        int tt = threadIdx.x;
        if (tt < 4)  wn[tt] = ldf(W_node, tt, fw);
        if (tt < 32) we[tt] = ldf(W_edge, tt, fw);
    }
    __syncthreads();

    int e = blockIdx.x * blockDim.x + threadIdx.x;
    if (e >= E) return;

    size_t sw = i64 ? (size_t)2 * e : (size_t)e;
    size_t dw = i64 ? ((size_t)2 * E + 2 * (size_t)e) : ((size_t)E + e);
    int s = ei[sw], d = ei[dw];

    float xs = ldf(x, s, fx), xd = ldf(x, d, fx);
    float l0 = xs * wn[0] + xd * wn[2];
    float l1 = xs * wn[1] + xd * wn[3];

    if (fe) {
        const uint4* p = (const uint4*)((const bf16*)ea + (size_t)e * 16);
        uint4 a = p[0], b = p[1];
        unsigned w[8] = {a.x, a.y, a.z, a.w, b.x, b.y, b.z, b.w};
#pragma unroll
        for (int k = 0; k < 8; ++k) {
            float lo = __uint_as_float(w[k] << 16);
            float hi = __uint_as_float(w[k] & 0xFFFF0000u);
            l0 += lo * we[4 * k + 0] + hi * we[4 * k + 2];
            l1 += lo * we[4 * k + 1] + hi * we[4 * k + 3];
        }
    } else {
        const float4* p = (const float4*)((const float*)ea + (size_t)e * 16);
#pragma unroll
        for (int q = 0; q < 4; ++q) {
            float4 v = p[q];
            l0 += v.x * we[8 * q + 0] + v.y * we[8 * q + 2] +
                  v.z * we[8 * q + 4] + v.w * we[8 * q + 6];
            l1 += v.x * we[8 * q + 1] + v.y * we[8 * q + 3] +
                  v.z * we[8 * q + 5] + v.w * we[8 * q + 7];
        }
    }

    float pp0 = l0 >= 0.f ? l0 : 0.2f * l0;  // leaky_relu(., 0.2)
    float pp1 = l1 >= 0.f ? l1 : 0.2f * l1;
    out_pp[e] = make_float2(pp0, pp1);

    float sc = fminf(pp0 - pp1, 80.f);   // clamp only guards f32 exp overflow
    float ex = expf(sc);

    if (packed) {
        ((float2*)tail)[e] = make_float2(ex, __int_as_float(d)); // passB: no ei re-read
    } else {
        tail[e] = ex;
    }

    unsigned rsel = l2mode ? (xccId() & 7u)
                           : ((unsigned)blockIdx.x & (unsigned)rmask);
    float* myrep = rep + (size_t)rsel * twoN;
    if (l2mode) {
        atomAddL2(myrep + 2 * d,     ex);        // denom  (L2-local RMW)
        atomAddL2(myrep + 2 * d + 1, ex * xs);   // numerator
    } else {
        atomAddDev(myrep + 2 * d,     ex);
        atomAddDev(myrep + 2 * d + 1, ex * xs);
    }
}

// Reduce replicas -> denom_tot (for passB) and node output directly.
__global__ void reduce_kernel(const float* __restrict__ rep,
                              float* __restrict__ denom_tot,
                              float* __restrict__ out_node,
                              const void* __restrict__ W,
                              const unsigned* __restrict__ flags,
                              int N, int twoN, int R)
{
    int n = blockIdx.x * blockDim.x + threadIdx.x;
    if (n >= N) return;
    const bool fw = flags[2] != 0;
    float den = 0.f, num = 0.f;
    for (int r = 0; r < R; ++r) {
        den += rep[(size_t)r * twoN + 2 * n];
        num += rep[(size_t)r * twoN + 2 * n + 1];
    }
    denom_tot[n] = den;
    float w0 = ldf(W, 0, fw);
    out_node[n] = w0 * num / (den + 1e-16f);
}

// Pass B (atomic-free): attn = ex / (denom_tot[dst] + 1e-16)
__global__ void passB_kernel(const int* __restrict__ ei,
                             const float* __restrict__ tail,
                             const float* __restrict__ denom_tot,
                             float* __restrict__ out_attn,
                             const unsigned* __restrict__ flags, int E, int packed)
{
    int e = blockIdx.x * blockDim.x + threadIdx.x;
    if (e >= E) return;
    if (packed) {
        float2 v = ((const float2*)tail)[e];
        int d = __float_as_int(v.y);
        out_attn[e] = v.x / (denom_tot[d] + 1e-16f);
    } else {
        const bool i64 = flags[3] != 0;
        size_t dw = i64 ? ((size_t)2 * E + 2 * (size_t)e) : ((size_t)E + e);
        int d = ei[dw];
        out_attn[e] = tail[e] / (denom_tot[d] + 1e-16f);
    }
}

extern "C" void kernel_launch(void* const* d_in, const int* in_sizes, int n_in,
                              void* d_out, int out_size, void* d_ws, size_t ws_size,
                              hipStream_t stream)
{
    const void* x      = d_in[0];
    const int*  ei     = (const int*)d_in[1];
    const void* ea     = d_in[2];
    const void* W      = d_in[3];
    const void* W_node = d_in[4];
    const void* W_edge = d_in[5];

    const int N = in_sizes[0];       // x is [N,1]
    const int E = in_sizes[1] / 2;   // edge_index is [2,E]
    const int twoN = 2 * N;

    // outputs (all f32): out[N] ++ attn[E] ++ pair_pred[2E]
    float*  out_node = (float*)d_out;
    float*  out_attn = out_node + N;
    float2* out_pp   = (float2*)(out_attn + E);

    // ws layout: flags[4] u32 | rep[R*2N] f32 | denom_tot[N] f32 | tail
    //   tail packed:   sd[E] float2  (ex, dst)
    //   tail unpacked: score[E] f32
    // L2-local atomics need one replica per XCD -> R must be 8.
    int R, l2mode, packed;
    size_t fixed8 = 16 + (size_t)8 * twoN * 4 + (size_t)N * 4;
    if (ws_size >= fixed8 + (size_t)E * 8) {
        R = 8; l2mode = 1; packed = 1;
    } else if (ws_size >= fixed8 + (size_t)E * 4) {
        R = 8; l2mode = 1; packed = 0;
    } else {
        l2mode = 0; packed = 0;
        R = 1;
        for (int cand = 8; cand > 1; cand >>= 1) {
            size_t need = 16 + (size_t)cand * twoN * 4 + (size_t)N * 4 + (size_t)E * 4;
            if (ws_size >= need) { R = cand; break; }
        }
    }
    const int rmask = R - 1;

    unsigned* flags     = (unsigned*)d_ws;
    float*    rep       = (float*)(flags + 4);
    float*    denom_tot = rep + (size_t)R * twoN;
    float*    tail      = denom_tot + N;

    hipMemsetAsync(rep, 0, (size_t)R * twoN * sizeof(float), stream);

    const int blk = 256;
    const int gE = (E + blk - 1) / blk;
    const int gN = (N + blk - 1) / blk;

    detect_kernel<<<1, 256, 0, stream>>>((const unsigned short*)x,
                                         (const unsigned short*)ea,
                                         (const unsigned short*)W_edge, ei, flags);
    passA_kernel<<<gE, blk, 0, stream>>>(x, ei, ea, W_node, W_edge,
                                         out_pp, tail, rep, flags,
                                         E, twoN, rmask, l2mode, packed);
    reduce_kernel<<<gN, blk, 0, stream>>>(rep, denom_tot, out_node, W, flags, N, twoN, R);
    passB_kernel<<<gE, blk, 0, stream>>>(ei, tail, denom_tot, out_attn, flags, E, packed);
}